// Round 2
// baseline (2684.054 us; speedup 1.0000x reference)
//
#include <hip/hip_runtime.h>
#include <stdint.h>

#define T_ 50

typedef float f32x4 __attribute__((ext_vector_type(4)));
typedef short s16x8 __attribute__((ext_vector_type(8)));

// ---------------- workspace byte offsets ----------------
#define WS_WIH   0u          // [4cg][256 col][256 k] bf16, col = gate*64+unit order
#define WS_WHH   524288u     // same layout
#define WS_WINIT 1048576u    // [4cg][128 col][256 k]: col<64 -> W_h1 rows, else W_h2
#define WS_WFC   1310720u    // [4cg][64 col][256 k]
#define WS_GPAD  1441792u    // [32][32] bf16, zero-padded G
#define WS_CNT   1443840u    // 64 x u32 barrier counters
#define WS_NEED  1444864u

// ---------------- LDS byte offsets (dynamic, 161280 total) ----------------
#define L_WHH 0              // [256][256] bf16 swizzled          131072
#define L_A1  131072         // [24][256] bf16 swizzled (Gh)       12288
#define L_A2  143360         // [24][256] bf16 swizzled (Gx next)  12288
#define L_ZR  155648         // [256] bf16 zero row                  512
#define L_HST 156160         // [64 unit][40] bf16 h stage          5120
#define L_TOT 161280

__device__ __forceinline__ uint32_t bfbits(float f){
  uint32_t u = __builtin_bit_cast(uint32_t, f);
  u += 0x7FFFu + ((u >> 16) & 1u);   // RNE
  return u >> 16;
}
__device__ __forceinline__ uint32_t pk2bf(float lo, float hi){
  return bfbits(lo) | (bfbits(hi) << 16);
}
__device__ __forceinline__ f32x4 mfma16(s16x8 a, s16x8 b, f32x4 c){
  return __builtin_amdgcn_mfma_f32_16x16x32_bf16(a, b, c, 0, 0, 0);
}
#define LOG2E 1.4426950408889634f
__device__ __forceinline__ float fexp2(float x){ return __builtin_amdgcn_exp2f(x); }
__device__ __forceinline__ float frcp_(float x){ return __builtin_amdgcn_rcpf(x); }
__device__ __forceinline__ float fsig(float x){ return frcp_(1.f + fexp2(-LOG2E * x)); }
__device__ __forceinline__ float ftanh_(float x){ return 1.f - 2.f * frcp_(1.f + fexp2(2.f * LOG2E * x)); }

// ---------------- prep: weight layout conversion ----------------
__global__ void prep_kernel(const float* __restrict__ G,
                            const float* __restrict__ Wih, const float* __restrict__ Whh,
                            const float* __restrict__ Wh1, const float* __restrict__ Wh2,
                            const float* __restrict__ Wfc, uint8_t* __restrict__ ws)
{
  const int tid = blockIdx.x * blockDim.x + threadIdx.x;
  const int nth = gridDim.x * blockDim.x;
  uint16_t* wih = (uint16_t*)(ws + WS_WIH);
  uint16_t* whh = (uint16_t*)(ws + WS_WHH);
  uint16_t* wini= (uint16_t*)(ws + WS_WINIT);
  uint16_t* wfc = (uint16_t*)(ws + WS_WFC);
  uint16_t* gp  = (uint16_t*)(ws + WS_GPAD);
  uint32_t* cnt = (uint32_t*)(ws + WS_CNT);

  for (int i = tid; i < 262144; i += nth){
    int cg = i >> 16, c = (i >> 8) & 255, k = i & 255;
    int row = (c >> 6)*256 + 64*cg + (c & 63);
    wih[i] = (uint16_t)bfbits(Wih[row*256 + k]);
    whh[i] = (uint16_t)bfbits(Whh[row*256 + k]);
  }
  for (int i = tid; i < 131072; i += nth){
    int cg = i >> 15, c = (i >> 8) & 127, k = i & 255;
    float v = (c < 64) ? Wh1[(64*cg + c)*256 + k] : Wh2[(64*cg + c - 64)*256 + k];
    wini[i] = (uint16_t)bfbits(v);
  }
  for (int i = tid; i < 65536; i += nth){
    int cg = i >> 14, c = (i >> 8) & 63, k = i & 255;
    wfc[i] = (uint16_t)bfbits(Wfc[(64*cg + c)*256 + k]);
  }
  for (int i = tid; i < 1024; i += nth){
    int n = i >> 5, m = i & 31;
    gp[i] = (n < 24 && m < 24) ? (uint16_t)bfbits(G[n*24 + m]) : (uint16_t)0;
  }
  if (tid < 64) cnt[tid] = 0;
}

// ---------------- persistent cooperative encoder ----------------
// grid 256 = 64 batches x 4 col-groups; block = cg*64 + b (same-XCD batch groups)
__global__ void __launch_bounds__(512, 1)
encoder_kernel(const float* __restrict__ x, uint8_t* __restrict__ ws,
               float* __restrict__ out,
               const float* __restrict__ bih, const float* __restrict__ bhh,
               const float* __restrict__ bh1, const float* __restrict__ bh2,
               const float* __restrict__ bfc)
{
  extern __shared__ uint8_t smem[];
  uint16_t* WHHL = (uint16_t*)(smem + L_WHH);
  uint16_t* A1   = (uint16_t*)(smem + L_A1);
  uint16_t* A2   = (uint16_t*)(smem + L_A2);
  uint16_t* ZR   = (uint16_t*)(smem + L_ZR);
  uint16_t* HST  = (uint16_t*)(smem + L_HST);

  const int tid = threadIdx.x;
  const int b   = blockIdx.x & 63;
  const int cg  = blockIdx.x >> 6;
  const int w   = tid >> 6;        // wave 0..7
  const int l   = tid & 63;
  const int l15 = l & 15;
  const int g   = l >> 4;
  const int Mt  = w >> 2;          // node tile
  const int ns  = w & 3;           // unit tile selector
  const int ul  = ns*16 + l15;     // unit local 0..63
  const int ug  = 64*cg + ul;      // unit global 0..255

  const uint16_t* WIH  = (const uint16_t*)(ws + WS_WIH)   + (size_t)cg*65536;
  const uint16_t* WINI = (const uint16_t*)(ws + WS_WINIT) + (size_t)cg*32768;
  const uint16_t* WFC  = (const uint16_t*)(ws + WS_WFC)   + (size_t)cg*16384;
  const uint16_t* GP   = (const uint16_t*)(ws + WS_GPAD);
  uint32_t* cnt = (uint32_t*)(ws + WS_CNT) + b;
  uint16_t* GhB = (uint16_t*)((uint8_t*)out + (size_t)b*24576);  // 2 x 6144 elems

  // ---- load W_hh slice into LDS (swizzled), zero ZR/HST
  {
    const uint8_t* src = ws + WS_WHH + (size_t)cg*131072;
    for (int i = tid*8; i < 65536; i += 4096){
      uint4 v = *(const uint4*)(src + (size_t)i*2);
      int col = i >> 8, k0 = i & 255;
      *(uint4*)&WHHL[col*256 + (k0 ^ ((col&7)<<3))] = v;
    }
  }
  for (int i = tid; i < 256;  i += 512) ZR[i] = 0;
  for (int i = tid; i < 2560; i += 512) HST[i] = 0;

  // constant G A-fragment for this lane
  s16x8 gfrag = *(const s16x8*)&GP[(Mt*16 + l15)*32 + g*8];

  const float bb0 = bih[ug]     + bhh[ug];
  const float bb1 = bih[256+ug] + bhh[256+ug];
  const float bb2 = bih[512+ug] + bhh[512+ug];
  const float bb3 = bih[768+ug] + bhh[768+ug];
  const float bh1l = bh1[ug], bh2l = bh2[ug], bfcl = bfc[ug];

  const int arow = Mt*16 + l15;
  const int sw   = (arow < 24) ? ((arow & 7) << 3) : 0;
  const uint16_t* a1row = (arow < 24) ? (A1 + arow*256) : ZR;
  const uint16_t* a2row = (arow < 24) ? (A2 + arow*256) : ZR;

  auto gx_stage = [&](const float* xt){
    #pragma unroll
    for (int jt = 0; jt < 4; jt++){
      int f = (jt*4 + ns)*16 + l15;
      s16x8 bfrag;
      if (g < 3){
        uint32_t p0 = pk2bf(xt[(g*8+0)*256+f], xt[(g*8+1)*256+f]);
        uint32_t p1 = pk2bf(xt[(g*8+2)*256+f], xt[(g*8+3)*256+f]);
        uint32_t p2 = pk2bf(xt[(g*8+4)*256+f], xt[(g*8+5)*256+f]);
        uint32_t p3 = pk2bf(xt[(g*8+6)*256+f], xt[(g*8+7)*256+f]);
        uint4 q; q.x = p0; q.y = p1; q.z = p2; q.w = p3;
        bfrag = __builtin_bit_cast(s16x8, q);
      } else {
        bfrag = (s16x8){0,0,0,0,0,0,0,0};
      }
      f32x4 zz = {0.f,0.f,0.f,0.f};
      f32x4 gx = mfma16(gfrag, bfrag, zz);
      #pragma unroll
      for (int r = 0; r < 4; r++){
        int node = Mt*16 + g*4 + r;
        if (node < 24) A2[node*256 + (f ^ ((node&7)<<3))] = (uint16_t)bfbits(gx[r]);
      }
    }
  };

  auto buildA1 = [&](const uint16_t* gsrc){
    for (int c = tid; c < 768; c += 512){
      int row = c >> 5, u8 = (c & 31)*8;
      uint4 v = *(const uint4*)(gsrc + row*256 + u8);
      *(uint4*)&A1[row*256 + (u8 ^ ((row&7)<<3))] = v;
    }
  };

  auto arrive = [&](){
    __threadfence();
    __syncthreads();
    if (tid == 0)
      __hip_atomic_fetch_add(cnt, 1u, __ATOMIC_RELEASE, __HIP_MEMORY_SCOPE_AGENT);
  };
  auto wait_for = [&](uint32_t target){
    if (tid == 0){
      uint64_t t0 = __builtin_amdgcn_s_memrealtime();
      while (__hip_atomic_load(cnt, __ATOMIC_ACQUIRE, __HIP_MEMORY_SCOPE_AGENT) < target){
        __builtin_amdgcn_s_sleep(1);
        if (__builtin_amdgcn_s_memrealtime() - t0 > 200000000ull) break;  // loud fail, no hang
      }
    }
    __syncthreads();
  };

  float cst[4];
  f32x4 zacc[4];

  // ---------- init: h0/c0 from Gx0; publish Gh0 to parity-1 slot ----------
  gx_stage(x + (size_t)b*T_*6144);
  __syncthreads();
  {
    f32x4 h0a = {0.f,0.f,0.f,0.f}, c0a = {0.f,0.f,0.f,0.f};
    #pragma unroll
    for (int j = 0; j < 4; j++) zacc[j] = (f32x4){0.f,0.f,0.f,0.f};
    #pragma unroll
    for (int ks = 0; ks < 8; ks++){
      s16x8 a  = *(const s16x8*)&a2row[(ks*32 + g*8) ^ sw];
      s16x8 b1 = *(const s16x8*)&WINI[ul*256 + ks*32 + g*8];
      s16x8 b2 = *(const s16x8*)&WINI[(64+ul)*256 + ks*32 + g*8];
      h0a = mfma16(a, b1, h0a);
      c0a = mfma16(a, b2, c0a);
      #pragma unroll
      for (int j = 0; j < 4; j++){
        s16x8 bz = *(const s16x8*)&WIH[((j*4+ns)*16 + l15)*256 + ks*32 + g*8];
        zacc[j] = mfma16(a, bz, zacc[j]);
      }
    }
    #pragma unroll
    for (int r = 0; r < 4; r++){
      cst[r] = c0a[r] + bh2l;
      int node = Mt*16 + g*4 + r;
      if (node < 24) HST[ul*40 + node] = (uint16_t)bfbits(h0a[r] + bh1l);
    }
  }
  __syncthreads();
  {
    s16x8 hb = *(const s16x8*)&HST[ul*40 + g*8];
    f32x4 zz = {0.f,0.f,0.f,0.f};
    f32x4 gh = mfma16(gfrag, hb, zz);
    uint16_t* gd = GhB + 6144;   // parity 1
    #pragma unroll
    for (int r = 0; r < 4; r++){
      int node = Mt*16 + g*4 + r;
      if (node < 24) gd[node*256 + ug] = (uint16_t)bfbits(gh[r]);
    }
  }
  arrive();
  wait_for(4);

  // ---------- recurrence ----------
  for (int t = 0; t < T_; t++){
    buildA1(GhB + ((t+1)&1)*6144);
    if (t+1 < T_) gx_stage(x + ((size_t)b*T_ + (t+1))*6144);
    __syncthreads();

    // u = z + Gh . W_hh^T   (B from LDS)
    f32x4 uacc[4];
    #pragma unroll
    for (int j = 0; j < 4; j++) uacc[j] = zacc[j];
    #pragma unroll
    for (int ks = 0; ks < 8; ks++){
      s16x8 a = *(const s16x8*)&a1row[(ks*32 + g*8) ^ sw];
      #pragma unroll
      for (int j = 0; j < 4; j++){
        int col = (j*4+ns)*16 + l15;
        s16x8 bf = *(const s16x8*)&WHHL[col*256 + ((ks*32 + g*8) ^ ((col&7)<<3))];
        uacc[j] = mfma16(a, bf, uacc[j]);
      }
    }
    // pointwise LSTM
    #pragma unroll
    for (int r = 0; r < 4; r++){
      float ig = fsig  (uacc[0][r] + bb0);
      float fg = fsig  (uacc[1][r] + bb1);
      float gg = ftanh_(uacc[2][r] + bb2);
      float og = fsig  (uacc[3][r] + bb3);
      float c  = fg*cst[r] + ig*gg;
      cst[r] = c;
      float h = og*ftanh_(c);
      int node = Mt*16 + g*4 + r;
      if (node < 24) HST[ul*40 + node] = (uint16_t)bfbits(h);
    }
    __syncthreads();
    // Gh = G . h  -> publish
    {
      s16x8 hb = *(const s16x8*)&HST[ul*40 + g*8];
      f32x4 zz = {0.f,0.f,0.f,0.f};
      f32x4 gh = mfma16(gfrag, hb, zz);
      uint16_t* gd = GhB + (t&1)*6144;
      #pragma unroll
      for (int r = 0; r < 4; r++){
        int node = Mt*16 + g*4 + r;
        if (node < 24) gd[node*256 + ug] = (uint16_t)bfbits(gh[r]);
      }
    }
    arrive();
    // z for next step (x-path, latency-tolerant, fills barrier slack)
    if (t+1 < T_){
      #pragma unroll
      for (int j = 0; j < 4; j++) zacc[j] = (f32x4){0.f,0.f,0.f,0.f};
      #pragma unroll
      for (int ks = 0; ks < 8; ks++){
        s16x8 a = *(const s16x8*)&a2row[(ks*32 + g*8) ^ sw];
        #pragma unroll
        for (int j = 0; j < 4; j++){
          s16x8 bf = *(const s16x8*)&WIH[((j*4+ns)*16 + l15)*256 + ks*32 + g*8];
          zacc[j] = mfma16(a, bf, zacc[j]);
        }
      }
    }
    wait_for(4*(t+2));
  }

  // ---------- final: out = tanh(Gh_final . W_fc^T + bfc) ----------
  buildA1(GhB + 6144);          // parity (T-1)&1 = 1
  arrive();                     // all 4 WGs done reading GhB before out overwrite
  wait_for(4*(T_+2));
  {
    f32x4 oacc = {0.f,0.f,0.f,0.f};
    #pragma unroll
    for (int ks = 0; ks < 8; ks++){
      s16x8 a  = *(const s16x8*)&a1row[(ks*32 + g*8) ^ sw];
      s16x8 bf = *(const s16x8*)&WFC[ul*256 + ks*32 + g*8];
      oacc = mfma16(a, bf, oacc);
    }
    #pragma unroll
    for (int r = 0; r < 4; r++){
      int node = Mt*16 + g*4 + r;
      if (node < 24)
        out[(size_t)b*6144 + node*256 + ug] = ftanh_(oacc[r] + bfcl);
    }
  }
}

extern "C" void kernel_launch(void* const* d_in, const int* in_sizes, int n_in,
                              void* d_out, int out_size, void* d_ws, size_t ws_size,
                              hipStream_t stream)
{
  (void)in_sizes; (void)n_in; (void)out_size;
  if (ws_size < WS_NEED) return;   // loud failure via validation rather than OOB

  const float* x   = (const float*)d_in[0];
  const float* G   = (const float*)d_in[1];
  const float* Wih = (const float*)d_in[2];
  const float* bih = (const float*)d_in[3];
  const float* Whh = (const float*)d_in[4];
  const float* bhh = (const float*)d_in[5];
  const float* Wh1 = (const float*)d_in[6];
  const float* bh1 = (const float*)d_in[7];
  const float* Wh2 = (const float*)d_in[8];
  const float* bh2 = (const float*)d_in[9];
  const float* Wfc = (const float*)d_in[10];
  const float* bfc = (const float*)d_in[11];
  uint8_t* ws = (uint8_t*)d_ws;
  float* outp = (float*)d_out;

  hipLaunchKernelGGL(prep_kernel, dim3(256), dim3(256), 0, stream,
                     G, Wih, Whh, Wh1, Wh2, Wfc, ws);

  hipFuncSetAttribute((const void*)encoder_kernel,
                      hipFuncAttributeMaxDynamicSharedMemorySize, L_TOT);
  void* args[] = {(void*)&x, (void*)&ws, (void*)&outp,
                  (void*)&bih, (void*)&bhh, (void*)&bh1, (void*)&bh2, (void*)&bfc};
  hipLaunchCooperativeKernel((const void*)encoder_kernel, dim3(256), dim3(512),
                             args, L_TOT, stream);
}

// Round 3
// 649.741 us; speedup vs baseline: 4.1310x; 4.1310x over previous
//
#include <hip/hip_runtime.h>
#include <stdint.h>

#define T_ 50

typedef float f32x4 __attribute__((ext_vector_type(4)));
typedef short s16x8 __attribute__((ext_vector_type(8)));

// ---------------- workspace byte offsets ----------------
#define WS_WIH   0u          // [4cg][256 col][256 k] bf16, col = gate*64+unit order
#define WS_WHH   524288u     // same layout
#define WS_WINIT 1048576u    // [4cg][128 col][256 k]: col<64 -> W_h1 rows, else W_h2
#define WS_WFC   1310720u    // [4cg][64 col][256 k]
#define WS_GPAD  1441792u    // [32][32] bf16, zero-padded G
#define WS_FLG   1443840u    // 64 batches x 4 cg flags, 64B stride each
#define WS_NEED  1460224u

// ---------------- LDS byte offsets (dynamic, 161280 total) ----------------
#define L_WHH 0              // [256][256] bf16 swizzled          131072
#define L_A1  131072         // [24][256] bf16 swizzled (Gh)       12288
#define L_A2  143360         // [24][256] bf16 swizzled (Gx next)  12288
#define L_ZR  155648         // [256] bf16 zero row                  512
#define L_HST 156160         // [64 unit][40] bf16 h stage          5120
#define L_TOT 161280

__device__ __forceinline__ uint32_t bfbits(float f){
  uint32_t u = __builtin_bit_cast(uint32_t, f);
  u += 0x7FFFu + ((u >> 16) & 1u);   // RNE
  return u >> 16;
}
__device__ __forceinline__ uint32_t pk2bf(float lo, float hi){
  return bfbits(lo) | (bfbits(hi) << 16);
}
__device__ __forceinline__ f32x4 mfma16(s16x8 a, s16x8 b, f32x4 c){
  return __builtin_amdgcn_mfma_f32_16x16x32_bf16(a, b, c, 0, 0, 0);
}
#define LOG2E 1.4426950408889634f
__device__ __forceinline__ float fexp2(float x){ return __builtin_amdgcn_exp2f(x); }
__device__ __forceinline__ float frcp_(float x){ return __builtin_amdgcn_rcpf(x); }
__device__ __forceinline__ float fsig(float x){ return frcp_(1.f + fexp2(-LOG2E * x)); }
__device__ __forceinline__ float ftanh_(float x){ return 1.f - 2.f * frcp_(1.f + fexp2(2.f * LOG2E * x)); }

// ---------------- prep: weight layout conversion ----------------
__global__ void prep_kernel(const float* __restrict__ G,
                            const float* __restrict__ Wih, const float* __restrict__ Whh,
                            const float* __restrict__ Wh1, const float* __restrict__ Wh2,
                            const float* __restrict__ Wfc, uint8_t* __restrict__ ws)
{
  const int tid = blockIdx.x * blockDim.x + threadIdx.x;
  const int nth = gridDim.x * blockDim.x;
  uint16_t* wih = (uint16_t*)(ws + WS_WIH);
  uint16_t* whh = (uint16_t*)(ws + WS_WHH);
  uint16_t* wini= (uint16_t*)(ws + WS_WINIT);
  uint16_t* wfc = (uint16_t*)(ws + WS_WFC);
  uint16_t* gp  = (uint16_t*)(ws + WS_GPAD);
  uint32_t* flg = (uint32_t*)(ws + WS_FLG);

  for (int i = tid; i < 262144; i += nth){
    int cg = i >> 16, c = (i >> 8) & 255, k = i & 255;
    int row = (c >> 6)*256 + 64*cg + (c & 63);
    wih[i] = (uint16_t)bfbits(Wih[row*256 + k]);
    whh[i] = (uint16_t)bfbits(Whh[row*256 + k]);
  }
  for (int i = tid; i < 131072; i += nth){
    int cg = i >> 15, c = (i >> 8) & 127, k = i & 255;
    float v = (c < 64) ? Wh1[(64*cg + c)*256 + k] : Wh2[(64*cg + c - 64)*256 + k];
    wini[i] = (uint16_t)bfbits(v);
  }
  for (int i = tid; i < 65536; i += nth){
    int cg = i >> 14, c = (i >> 8) & 63, k = i & 255;
    wfc[i] = (uint16_t)bfbits(Wfc[(64*cg + c)*256 + k]);
  }
  for (int i = tid; i < 1024; i += nth){
    int n = i >> 5, m = i & 31;
    gp[i] = (n < 24 && m < 24) ? (uint16_t)bfbits(G[n*24 + m]) : (uint16_t)0;
  }
  for (int i = tid; i < 4096; i += nth) flg[i] = 0;
}

// ---------------- persistent cooperative encoder ----------------
// grid 256 = 64 batches x 4 col-groups
__global__ void __launch_bounds__(512, 1)
encoder_kernel(const float* __restrict__ x, uint8_t* __restrict__ ws,
               float* __restrict__ out,
               const float* __restrict__ bih, const float* __restrict__ bhh,
               const float* __restrict__ bh1, const float* __restrict__ bh2,
               const float* __restrict__ bfc)
{
  extern __shared__ uint8_t smem[];
  uint16_t* WHHL = (uint16_t*)(smem + L_WHH);
  uint16_t* A1   = (uint16_t*)(smem + L_A1);
  uint16_t* A2   = (uint16_t*)(smem + L_A2);
  uint16_t* ZR   = (uint16_t*)(smem + L_ZR);
  uint16_t* HST  = (uint16_t*)(smem + L_HST);

  const int tid = threadIdx.x;
  const int b   = blockIdx.x & 63;
  const int cg  = blockIdx.x >> 6;
  const int w   = tid >> 6;        // wave 0..7
  const int l   = tid & 63;
  const int l15 = l & 15;
  const int g   = l >> 4;
  const int Mt  = w >> 2;          // node tile
  const int ns  = w & 3;           // unit tile selector
  const int ul  = ns*16 + l15;     // unit local 0..63
  const int ug  = 64*cg + ul;      // unit global 0..255

  const uint16_t* WIH  = (const uint16_t*)(ws + WS_WIH)   + (size_t)cg*65536;
  const uint16_t* WINI = (const uint16_t*)(ws + WS_WINIT) + (size_t)cg*32768;
  const uint16_t* WFC  = (const uint16_t*)(ws + WS_WFC)   + (size_t)cg*16384;
  const uint16_t* GP   = (const uint16_t*)(ws + WS_GPAD);
  uint32_t* flg   = (uint32_t*)(ws + WS_FLG) + b*64;   // 4 flags, 16-u32 stride
  uint32_t* myflg = flg + cg*16;
  uint16_t* GhB = (uint16_t*)((uint8_t*)out + (size_t)b*24576);  // 2 parity x 6144
  // Gh slot layout (per parity): [cg][64 unit][24 node] bf16

  // ---- load W_hh slice into LDS (swizzled), zero ZR/HST
  {
    const uint8_t* src = ws + WS_WHH + (size_t)cg*131072;
    for (int i = tid*8; i < 65536; i += 4096){
      uint4 v = *(const uint4*)(src + (size_t)i*2);
      int col = i >> 8, k0 = i & 255;
      *(uint4*)&WHHL[col*256 + (k0 ^ ((col&7)<<3))] = v;
    }
  }
  for (int i = tid; i < 256;  i += 512) ZR[i] = 0;
  for (int i = tid; i < 2560; i += 512) HST[i] = 0;

  // constant G A-fragment for this lane
  s16x8 gfrag = *(const s16x8*)&GP[(Mt*16 + l15)*32 + g*8];

  const float bb0 = bih[ug]     + bhh[ug];
  const float bb1 = bih[256+ug] + bhh[256+ug];
  const float bb2 = bih[512+ug] + bhh[512+ug];
  const float bb3 = bih[768+ug] + bhh[768+ug];
  const float bh1l = bh1[ug], bh2l = bh2[ug], bfcl = bfc[ug];

  const int arow = Mt*16 + l15;
  const int sw   = (arow < 24) ? ((arow & 7) << 3) : 0;
  const uint16_t* a1row = (arow < 24) ? (A1 + arow*256) : ZR;
  const uint16_t* a2row = (arow < 24) ? (A2 + arow*256) : ZR;

  auto gx_stage = [&](const float* xt){
    #pragma unroll
    for (int jt = 0; jt < 4; jt++){
      int f = (jt*4 + ns)*16 + l15;
      s16x8 bfrag;
      if (g < 3){
        uint32_t p0 = pk2bf(xt[(g*8+0)*256+f], xt[(g*8+1)*256+f]);
        uint32_t p1 = pk2bf(xt[(g*8+2)*256+f], xt[(g*8+3)*256+f]);
        uint32_t p2 = pk2bf(xt[(g*8+4)*256+f], xt[(g*8+5)*256+f]);
        uint32_t p3 = pk2bf(xt[(g*8+6)*256+f], xt[(g*8+7)*256+f]);
        uint4 q; q.x = p0; q.y = p1; q.z = p2; q.w = p3;
        bfrag = __builtin_bit_cast(s16x8, q);
      } else {
        bfrag = (s16x8){0,0,0,0,0,0,0,0};
      }
      f32x4 zz = {0.f,0.f,0.f,0.f};
      f32x4 gx = mfma16(gfrag, bfrag, zz);
      #pragma unroll
      for (int r = 0; r < 4; r++){
        int node = Mt*16 + g*4 + r;
        if (node < 24) A2[node*256 + (f ^ ((node&7)<<3))] = (uint16_t)bfbits(gx[r]);
      }
    }
  };

  // read full Gh slot (MALL-coherent) into swizzled A1
  auto buildA1 = [&](int parity){
    const unsigned long long* gsrc = (const unsigned long long*)(GhB + parity*6144);
    for (int w_ = tid; w_ < 1536; w_ += 512){
      unsigned long long v = __hip_atomic_load((unsigned long long*)(gsrc + w_),
                              __ATOMIC_RELAXED, __HIP_MEMORY_SCOPE_AGENT);
      int cgs  = w_ / 384;
      int rem  = w_ - cgs*384;
      int unit = rem / 6;
      int node0= (rem - unit*6)*4;
      int k    = cgs*64 + unit;
      #pragma unroll
      for (int j = 0; j < 4; j++){
        int node = node0 + j;
        A1[node*256 + (k ^ ((node&7)<<3))] = (uint16_t)(v >> (16*j));
      }
    }
  };

  // compute Gh from HST and publish own [unit][node] slice + flag
  auto publish = [&](int parity, uint32_t flagval){
    s16x8 hb = *(const s16x8*)&HST[ul*40 + g*8];
    f32x4 zz = {0.f,0.f,0.f,0.f};
    f32x4 gh = mfma16(gfrag, hb, zz);
    int node0 = Mt*16 + g*4;
    if (node0 < 24){
      unsigned long long pv = (unsigned long long)pk2bf(gh[0], gh[1])
                            | ((unsigned long long)pk2bf(gh[2], gh[3]) << 32);
      unsigned long long* gd = (unsigned long long*)(GhB + parity*6144);
      __hip_atomic_store(gd + (cg*1536 + ul*24 + node0)/4, pv,
                         __ATOMIC_RELAXED, __HIP_MEMORY_SCOPE_AGENT);
    }
    asm volatile("s_waitcnt vmcnt(0)" ::: "memory");
    __syncthreads();
    if (tid == 0)
      __hip_atomic_store(myflg, flagval, __ATOMIC_RELAXED, __HIP_MEMORY_SCOPE_AGENT);
  };

  auto wait_for = [&](uint32_t target){
    if (tid < 4){
      uint32_t* fp = flg + tid*16;
      int guard = 0;
      while (__hip_atomic_load(fp, __ATOMIC_RELAXED, __HIP_MEMORY_SCOPE_AGENT) < target){
        __builtin_amdgcn_s_sleep(1);
        if (++guard > 50000000) break;    // loud fail (wrong result), no hang
      }
    }
    __syncthreads();
  };

  float cst[4];
  f32x4 zacc[4];

  // ---------- init: h0/c0 from Gx0; z0; publish Gh0 to parity-1 ----------
  gx_stage(x + (size_t)b*T_*6144);
  __syncthreads();
  {
    f32x4 h0a = {0.f,0.f,0.f,0.f}, c0a = {0.f,0.f,0.f,0.f};
    #pragma unroll
    for (int j = 0; j < 4; j++) zacc[j] = (f32x4){0.f,0.f,0.f,0.f};
    #pragma unroll
    for (int ks = 0; ks < 8; ks++){
      s16x8 a  = *(const s16x8*)&a2row[(ks*32 + g*8) ^ sw];
      s16x8 b1 = *(const s16x8*)&WINI[ul*256 + ks*32 + g*8];
      s16x8 b2 = *(const s16x8*)&WINI[(64+ul)*256 + ks*32 + g*8];
      h0a = mfma16(a, b1, h0a);
      c0a = mfma16(a, b2, c0a);
      #pragma unroll
      for (int j = 0; j < 4; j++){
        s16x8 bz = *(const s16x8*)&WIH[((j*4+ns)*16 + l15)*256 + ks*32 + g*8];
        zacc[j] = mfma16(a, bz, zacc[j]);
      }
    }
    #pragma unroll
    for (int r = 0; r < 4; r++){
      cst[r] = c0a[r] + bh2l;
      int node = Mt*16 + g*4 + r;
      if (node < 24) HST[ul*40 + node] = (uint16_t)bfbits(h0a[r] + bh1l);
    }
  }
  __syncthreads();
  publish(1, 1u);

  // ---------- recurrence ----------
  for (int t = 0; t < T_; t++){
    wait_for((uint32_t)(t+1));
    buildA1((t+1)&1);
    __syncthreads();

    // u = z + Gh . W_hh^T   (B from LDS)
    f32x4 uacc[4];
    #pragma unroll
    for (int j = 0; j < 4; j++) uacc[j] = zacc[j];
    #pragma unroll
    for (int ks = 0; ks < 8; ks++){
      s16x8 a = *(const s16x8*)&a1row[(ks*32 + g*8) ^ sw];
      #pragma unroll
      for (int j = 0; j < 4; j++){
        int col = (j*4+ns)*16 + l15;
        s16x8 bf = *(const s16x8*)&WHHL[col*256 + ((ks*32 + g*8) ^ ((col&7)<<3))];
        uacc[j] = mfma16(a, bf, uacc[j]);
      }
    }
    // pointwise LSTM
    #pragma unroll
    for (int r = 0; r < 4; r++){
      float ig = fsig  (uacc[0][r] + bb0);
      float fg = fsig  (uacc[1][r] + bb1);
      float gg = ftanh_(uacc[2][r] + bb2);
      float og = fsig  (uacc[3][r] + bb3);
      float c  = fg*cst[r] + ig*gg;
      cst[r] = c;
      float h = og*ftanh_(c);
      int node = Mt*16 + g*4 + r;
      if (node < 24) HST[ul*40 + node] = (uint16_t)bfbits(h);
    }
    __syncthreads();
    publish(t & 1, (uint32_t)(t+2));

    // slack work (off critical path): x-path for step t+1
    if (t+1 < T_){
      gx_stage(x + ((size_t)b*T_ + (t+1))*6144);
      __syncthreads();
      #pragma unroll
      for (int j = 0; j < 4; j++) zacc[j] = (f32x4){0.f,0.f,0.f,0.f};
      #pragma unroll
      for (int ks = 0; ks < 8; ks++){
        s16x8 a = *(const s16x8*)&a2row[(ks*32 + g*8) ^ sw];
        #pragma unroll
        for (int j = 0; j < 4; j++){
          s16x8 bf = *(const s16x8*)&WIH[((j*4+ns)*16 + l15)*256 + ks*32 + g*8];
          zacc[j] = mfma16(a, bf, zacc[j]);
        }
      }
    }
  }

  // ---------- final: out = tanh(Gh_final . W_fc^T + bfc) ----------
  wait_for((uint32_t)(T_+1));
  buildA1(1);                 // parity (T-1)&1 = 1
  __syncthreads();            // A1 ready; all our Gh reads complete
  if (tid == 0)
    __hip_atomic_store(myflg, (uint32_t)(T_+2), __ATOMIC_RELAXED, __HIP_MEMORY_SCOPE_AGENT);
  wait_for((uint32_t)(T_+2)); // all 4 WGs done reading GhB -> safe to overwrite out
  {
    f32x4 oacc = {0.f,0.f,0.f,0.f};
    #pragma unroll
    for (int ks = 0; ks < 8; ks++){
      s16x8 a  = *(const s16x8*)&a1row[(ks*32 + g*8) ^ sw];
      s16x8 bf = *(const s16x8*)&WFC[ul*256 + ks*32 + g*8];
      oacc = mfma16(a, bf, oacc);
    }
    #pragma unroll
    for (int r = 0; r < 4; r++){
      int node = Mt*16 + g*4 + r;
      if (node < 24)
        out[(size_t)b*6144 + node*256 + ug] = ftanh_(oacc[r] + bfcl);
    }
  }
}

extern "C" void kernel_launch(void* const* d_in, const int* in_sizes, int n_in,
                              void* d_out, int out_size, void* d_ws, size_t ws_size,
                              hipStream_t stream)
{
  (void)in_sizes; (void)n_in; (void)out_size;
  if (ws_size < WS_NEED) return;   // loud failure via validation rather than OOB

  const float* x   = (const float*)d_in[0];
  const float* G   = (const float*)d_in[1];
  const float* Wih = (const float*)d_in[2];
  const float* bih = (const float*)d_in[3];
  const float* Whh = (const float*)d_in[4];
  const float* bhh = (const float*)d_in[5];
  const float* Wh1 = (const float*)d_in[6];
  const float* bh1 = (const float*)d_in[7];
  const float* Wh2 = (const float*)d_in[8];
  const float* bh2 = (const float*)d_in[9];
  const float* Wfc = (const float*)d_in[10];
  const float* bfc = (const float*)d_in[11];
  uint8_t* ws = (uint8_t*)d_ws;
  float* outp = (float*)d_out;

  hipLaunchKernelGGL(prep_kernel, dim3(256), dim3(256), 0, stream,
                     G, Wih, Whh, Wh1, Wh2, Wfc, ws);

  hipFuncSetAttribute((const void*)encoder_kernel,
                      hipFuncAttributeMaxDynamicSharedMemorySize, L_TOT);
  void* args[] = {(void*)&x, (void*)&ws, (void*)&outp,
                  (void*)&bih, (void*)&bhh, (void*)&bh1, (void*)&bh2, (void*)&bfc};
  hipLaunchCooperativeKernel((const void*)encoder_kernel, dim3(256), dim3(512),
                             args, L_TOT, stream);
}

// Round 7
// 642.399 us; speedup vs baseline: 4.1782x; 1.0114x over previous
//
#include <hip/hip_runtime.h>
#include <stdint.h>

#define T_ 50

typedef float f32x4 __attribute__((ext_vector_type(4)));
typedef short s16x8 __attribute__((ext_vector_type(8)));

// ---------------- workspace byte offsets ----------------
#define WS_WIH   0u          // [4cg][256 col][256 k] bf16, col = gate*64+unit order
#define WS_WHH   524288u     // same layout
#define WS_WINIT 1048576u    // [4cg][128 col][256 k]: col<64 -> W_h1 rows, else W_h2
#define WS_WFC   1310720u    // [4cg][64 col][256 k]
#define WS_GPAD  1441792u    // [32][32] bf16, zero-padded G
#define WS_FLG   1443840u    // flags: [64 b][4 cg] u32, 64B stride
#define WS_NEED  1460224u

// ---------------- LDS byte offsets (dynamic, 163328 B) ----------------
#define L_WHH  0             // [256][256] bf16 swizzled           131072
#define L_A1   131072        // [24][256] bf16 swizzled (Gh)        12288
#define L_A2   143360        // [24][256] bf16 swizzled (Gx)        12288
#define L_ZR   155648        // [256] bf16 zero row                   512
#define L_HST  156160        // [64 unit][32 node] bf16 h stage      4096
#define L_HST2 160256        // [24 node][64 unit] bf16 Gh transp    3072
#define L_TOT  163328

__device__ __forceinline__ f32x4 mfma16(s16x8 a, s16x8 b, f32x4 c){
  return __builtin_amdgcn_mfma_f32_16x16x32_bf16(a, b, c, 0, 0, 0);
}
__device__ __forceinline__ uint32_t bfbits(float f){
  uint32_t u = __builtin_bit_cast(uint32_t, f);
  u += 0x7FFFu + ((u >> 16) & 1u);   // RNE
  return u >> 16;
}
__device__ __forceinline__ uint32_t pk2bf(float lo, float hi){
  return bfbits(lo) | (bfbits(hi) << 16);
}
#define LOG2E 1.4426950408889634f
__device__ __forceinline__ float fexp2(float x){ return __builtin_amdgcn_exp2f(x); }
__device__ __forceinline__ float frcp_(float x){ return __builtin_amdgcn_rcpf(x); }
__device__ __forceinline__ float fsig(float x){ return frcp_(1.f + fexp2(-LOG2E * x)); }
__device__ __forceinline__ float ftanh_(float x){ return 1.f - 2.f * frcp_(1.f + fexp2(2.f * LOG2E * x)); }

// ---------------- prep: weight layout conversion ----------------
__global__ void prep_kernel(const float* __restrict__ G,
                            const float* __restrict__ Wih, const float* __restrict__ Whh,
                            const float* __restrict__ Wh1, const float* __restrict__ Wh2,
                            const float* __restrict__ Wfc, uint8_t* __restrict__ ws)
{
  const int tid = blockIdx.x * blockDim.x + threadIdx.x;
  const int nth = gridDim.x * blockDim.x;
  uint16_t* wih = (uint16_t*)(ws + WS_WIH);
  uint16_t* whh = (uint16_t*)(ws + WS_WHH);
  uint16_t* wini= (uint16_t*)(ws + WS_WINIT);
  uint16_t* wfc = (uint16_t*)(ws + WS_WFC);
  uint16_t* gp  = (uint16_t*)(ws + WS_GPAD);
  uint32_t* flg = (uint32_t*)(ws + WS_FLG);

  for (int i = tid; i < 262144; i += nth){
    int cg = i >> 16, c = (i >> 8) & 255, k = i & 255;
    int row = (c >> 6)*256 + 64*cg + (c & 63);
    wih[i] = (uint16_t)bfbits(Wih[row*256 + k]);
    whh[i] = (uint16_t)bfbits(Whh[row*256 + k]);
  }
  for (int i = tid; i < 131072; i += nth){
    int cg = i >> 15, c = (i >> 8) & 127, k = i & 255;
    float v = (c < 64) ? Wh1[(64*cg + c)*256 + k] : Wh2[(64*cg + c - 64)*256 + k];
    wini[i] = (uint16_t)bfbits(v);
  }
  for (int i = tid; i < 65536; i += nth){
    int cg = i >> 14, c = (i >> 8) & 63, k = i & 255;
    wfc[i] = (uint16_t)bfbits(Wfc[(64*cg + c)*256 + k]);
  }
  for (int i = tid; i < 1024; i += nth){
    int n = i >> 5, m = i & 31;
    gp[i] = (n < 24 && m < 24) ? (uint16_t)bfbits(G[n*24 + m]) : (uint16_t)0;
  }
  for (int i = tid; i < 4096; i += nth) flg[i] = 0;
}

// ---------------- persistent cooperative encoder ----------------
// grid 256 = 64 batches x 4 col-groups; 8 uniform waves: Mt=w>>2, ns=w&3
__global__ void __launch_bounds__(512, 1)
encoder_kernel(const float* __restrict__ x, uint8_t* __restrict__ ws,
               float* __restrict__ out,
               const float* __restrict__ bih, const float* __restrict__ bhh,
               const float* __restrict__ bh1, const float* __restrict__ bh2,
               const float* __restrict__ bfc)
{
  extern __shared__ uint8_t smem[];
  uint16_t* WHHL = (uint16_t*)(smem + L_WHH);
  uint16_t* A1   = (uint16_t*)(smem + L_A1);
  uint16_t* A2   = (uint16_t*)(smem + L_A2);
  uint16_t* ZR   = (uint16_t*)(smem + L_ZR);
  uint16_t* HST  = (uint16_t*)(smem + L_HST);
  uint16_t* HST2 = (uint16_t*)(smem + L_HST2);

  const int tid = threadIdx.x;
  const int b   = blockIdx.x & 63;
  const int cg  = blockIdx.x >> 6;
  const int w   = tid >> 6;
  const int l   = tid & 63;
  const int l15 = l & 15;
  const int g   = l >> 4;
  const int Mt  = w >> 2;          // node tile (0: nodes 0-15, 1: 16-23)
  const int ns  = w & 3;           // unit tile
  const int ul  = ns*16 + l15;     // unit local 0..63
  const int ug  = 64*cg + ul;      // unit global

  const uint16_t* WIH  = (const uint16_t*)(ws + WS_WIH)   + (size_t)cg*65536;
  const uint16_t* WINI = (const uint16_t*)(ws + WS_WINIT) + (size_t)cg*32768;
  const uint16_t* WFC  = (const uint16_t*)(ws + WS_WFC)   + (size_t)cg*16384;
  const uint16_t* GP   = (const uint16_t*)(ws + WS_GPAD);
  uint32_t* flgB = (uint32_t*)(ws + WS_FLG) + b*64;   // 4 flags, 16-u32 stride
  uint32_t* flgW = flgB + cg*16;
  uint16_t* GhB  = (uint16_t*)((uint8_t*)out + (size_t)b*24576); // 2 parity x [24 node][256 unit]

  // ---- load W_hh slice into LDS (swizzled)
  {
    const uint8_t* src = ws + WS_WHH + (size_t)cg*131072;
    for (int i = tid*8; i < 65536; i += 4096){
      uint4 v = *(const uint4*)(src + (size_t)i*2);
      int col = i >> 8, k0 = i & 255;
      *(uint4*)&WHHL[col*256 + (k0 ^ ((col&7)<<3))] = v;
    }
  }
  for (int i = tid; i < 256;  i += 512) ZR[i] = 0;
  // zero ALL of HST: slots 24-31 of each row feed the Gh MFMA k-pad
  for (int i = tid; i < 2048; i += 512) HST[i] = 0;

  // constant G A-fragment for this wave's node tile
  s16x8 gfragM = *(const s16x8*)&GP[(Mt*16 + l15)*32 + g*8];

  const float bb0 = bih[ug]     + bhh[ug];
  const float bb1 = bih[256+ug] + bhh[256+ug];
  const float bb2 = bih[512+ug] + bhh[512+ug];
  const float bb3 = bih[768+ug] + bhh[768+ug];
  const float bh1l = bh1[ug], bh2l = bh2[ug], bfcl = bfc[ug];

  const int arow = Mt*16 + l15;
  const uint16_t* a1row = (arow < 24) ? (A1 + arow*256) : ZR;
  const uint16_t* a2row = (arow < 24) ? (A2 + arow*256) : ZR;
  const int sw = (arow < 24) ? ((arow & 7) << 3) : 0;

  // stage Gx[t] into A2 (swizzled), own Mt rows (proven r3 packing)
  auto gx_stage = [&](const float* xt){
    #pragma unroll
    for (int jt = 0; jt < 4; jt++){
      int f = (jt*4 + ns)*16 + l15;
      s16x8 bfrag = (s16x8){0,0,0,0,0,0,0,0};
      if (g < 3){
        uint4 q;
        q.x = pk2bf(xt[(g*8+0)*256+f], xt[(g*8+1)*256+f]);
        q.y = pk2bf(xt[(g*8+2)*256+f], xt[(g*8+3)*256+f]);
        q.z = pk2bf(xt[(g*8+4)*256+f], xt[(g*8+5)*256+f]);
        q.w = pk2bf(xt[(g*8+6)*256+f], xt[(g*8+7)*256+f]);
        bfrag = __builtin_bit_cast(s16x8, q);
      }
      f32x4 zz = {0.f,0.f,0.f,0.f};
      f32x4 gx = mfma16(gfragM, bfrag, zz);
      int n0 = Mt*16 + g*4;
      if (n0 < 24){
        uint32_t a01 = pk2bf(gx[0], gx[1]), a23 = pk2bf(gx[2], gx[3]);
        A2[(n0  )*256 + (f ^ (((n0  )&7)<<3))] = (uint16_t)a01;
        A2[(n0+1)*256 + (f ^ (((n0+1)&7)<<3))] = (uint16_t)(a01>>16);
        A2[(n0+2)*256 + (f ^ (((n0+2)&7)<<3))] = (uint16_t)a23;
        A2[(n0+3)*256 + (f ^ (((n0+3)&7)<<3))] = (uint16_t)(a23>>16);
      }
    }
  };

  // stage Gh (MALL) -> A1 swizzled: 1536 u64, 3 per thread, aligned u64 writes
  auto stageA1 = [&](int parity){
    const unsigned long long* gs = (const unsigned long long*)(GhB + parity*6144);
    unsigned long long v0 = __hip_atomic_load(gs + tid,        __ATOMIC_RELAXED, __HIP_MEMORY_SCOPE_AGENT);
    unsigned long long v1 = __hip_atomic_load(gs + tid + 512,  __ATOMIC_RELAXED, __HIP_MEMORY_SCOPE_AGENT);
    unsigned long long v2 = __hip_atomic_load(gs + tid + 1024, __ATOMIC_RELAXED, __HIP_MEMORY_SCOPE_AGENT);
    int k0 = (tid & 63) << 2;
    int n0 = tid >> 6, n1 = n0 + 8, n2 = n0 + 16;
    *(unsigned long long*)&A1[n0*256 + (k0 ^ ((n0&7)<<3))] = v0;
    *(unsigned long long*)&A1[n1*256 + (k0 ^ ((n1&7)<<3))] = v1;
    *(unsigned long long*)&A1[n2*256 + (k0 ^ ((n2&7)<<3))] = v2;
  };

  auto wait_for = [&](uint32_t target){
    if (tid < 4){
      uint32_t* fp = flgB + tid*16;
      int guard = 0;
      while (__hip_atomic_load(fp, __ATOMIC_RELAXED, __HIP_MEMORY_SCOPE_AGENT) < target){
        __builtin_amdgcn_s_sleep(1);
        if (++guard > 20000000) break;   // loud fail (wrong result), no hang
      }
    }
    __syncthreads();
  };

  // publish: h -> HST -> (P1) -> Gh MFMA -> HST2 -> (P2) -> u64 stores ->
  // vmcnt -> (P3) -> flag. Called UNCONDITIONALLY by all waves.
  auto do_publish = [&](const float hv[4], int parity, uint32_t flagval){
    int n0 = Mt*16 + g*4;
    if (n0 < 24){
      uint2 p; p.x = pk2bf(hv[0], hv[1]); p.y = pk2bf(hv[2], hv[3]);
      *(uint2*)&HST[ul*32 + n0] = p;     // n0 % 4 == 0 -> 8B aligned
    }
    __syncthreads();                                   // P1 (also fences A1/A2 reads)
    s16x8 hb = *(const s16x8*)&HST[ul*32 + g*8];
    f32x4 zz = {0.f,0.f,0.f,0.f};
    f32x4 gh = mfma16(gfragM, hb, zz);
    if (n0 < 24){
      uint32_t q01 = pk2bf(gh[0], gh[1]), q23 = pk2bf(gh[2], gh[3]);
      HST2[(n0  )*64 + ul] = (uint16_t)q01;
      HST2[(n0+1)*64 + ul] = (uint16_t)(q01>>16);
      HST2[(n0+2)*64 + ul] = (uint16_t)q23;
      HST2[(n0+3)*64 + ul] = (uint16_t)(q23>>16);
    }
    __syncthreads();                                   // P2: HST2 complete
    if (tid < 384){
      int node = tid >> 4, c4 = tid & 15;
      unsigned long long v = *(const unsigned long long*)&HST2[node*64 + c4*4];
      __hip_atomic_store((unsigned long long*)(GhB + parity*6144) + node*64 + cg*16 + c4,
                         v, __ATOMIC_RELAXED, __HIP_MEMORY_SCOPE_AGENT);
    }
    asm volatile("s_waitcnt vmcnt(0)" ::: "memory");
    __syncthreads();                                   // P3: all waves drained
    if (tid == 0)
      __hip_atomic_store(flgW, flagval, __ATOMIC_RELAXED, __HIP_MEMORY_SCOPE_AGENT);
  };

  float cst[4];
  f32x4 zacc[4];

  // ---------- init: Gx0 -> h0/c0/z0; publish Gh0 to parity 1 ----------
  gx_stage(x + (size_t)b*T_*6144);
  __syncthreads();                                     // I1
  {
    f32x4 h0a = {0.f,0.f,0.f,0.f}, c0a = {0.f,0.f,0.f,0.f};
    #pragma unroll
    for (int j = 0; j < 4; j++) zacc[j] = (f32x4){0.f,0.f,0.f,0.f};
    #pragma unroll
    for (int ks = 0; ks < 8; ks++){
      const int kk = ks*32 + g*8;
      s16x8 a  = *(const s16x8*)&a2row[kk ^ sw];
      s16x8 b1 = *(const s16x8*)&WINI[ul*256 + kk];
      s16x8 b2 = *(const s16x8*)&WINI[(64+ul)*256 + kk];
      h0a = mfma16(a, b1, h0a);
      c0a = mfma16(a, b2, c0a);
      #pragma unroll
      for (int j = 0; j < 4; j++){
        s16x8 bz = *(const s16x8*)&WIH[((j*4+ns)*16 + l15)*256 + kk];
        zacc[j] = mfma16(a, bz, zacc[j]);
      }
    }
    float hv0[4];
    #pragma unroll
    for (int r = 0; r < 4; r++){
      cst[r] = c0a[r] + bh2l;
      hv0[r] = h0a[r] + bh1l;
    }
    do_publish(hv0, 1, 1u);
  }
  gx_stage(x + ((size_t)b*T_ + 1)*6144);               // Gx[1] (A2 reads fenced by P1)

  // ---------- recurrence ----------
  for (int t = 0; t < T_; t++){
    wait_for((uint32_t)(t+1));                         // Gh_t published by all WGs
    stageA1((t+1)&1);
    __syncthreads();                                   // A1 ready

    f32x4 uacc[4];
    #pragma unroll
    for (int j = 0; j < 4; j++) uacc[j] = zacc[j];     // z_t from registers (f32)
    #pragma unroll
    for (int ks = 0; ks < 8; ks++){
      const int kk = ks*32 + g*8;
      s16x8 a = *(const s16x8*)&a1row[kk ^ sw];
      #pragma unroll
      for (int j = 0; j < 4; j++){
        int col = (j*4+ns)*16 + l15;
        s16x8 bf = *(const s16x8*)&WHHL[col*256 + (kk ^ ((col&7)<<3))];
        uacc[j] = mfma16(a, bf, uacc[j]);
      }
    }
    float hv[4];
    #pragma unroll
    for (int r = 0; r < 4; r++){
      float ig = fsig  (uacc[0][r] + bb0);
      float fg = fsig  (uacc[1][r] + bb1);
      float gg = ftanh_(uacc[2][r] + bb2);
      float og = fsig  (uacc[3][r] + bb3);
      float c  = fg*cst[r] + ig*gg;
      cst[r] = c;
      hv[r] = og*ftanh_(c);
    }
    do_publish(hv, t & 1, (uint32_t)(t+2));

    // local slack work: z_{t+1} from A2=Gx[t+1], then stage Gx[t+2]
    if (t+1 < T_){
      #pragma unroll
      for (int j = 0; j < 4; j++) zacc[j] = (f32x4){0.f,0.f,0.f,0.f};
      #pragma unroll
      for (int ks = 0; ks < 8; ks++){
        const int kk = ks*32 + g*8;
        s16x8 a = *(const s16x8*)&a2row[kk ^ sw];
        #pragma unroll
        for (int j = 0; j < 4; j++){
          s16x8 bf = *(const s16x8*)&WIH[((j*4+ns)*16 + l15)*256 + kk];
          zacc[j] = mfma16(a, bf, zacc[j]);
        }
      }
    }
    __syncthreads();                                   // S1: A2 reads complete
    if (t+1 < T_){
      int tn = (t+2 < T_) ? (t+2) : (T_-1);
      gx_stage(x + ((size_t)b*T_ + tn)*6144);          // Gx[t+2]
    }
  }

  // ---------- final: out = tanh(Gh_final . W_fc^T + bfc) ----------
  wait_for((uint32_t)(T_+1));
  stageA1(1);                                          // Gh_T (parity (T-1)&1 = 1)
  __syncthreads();                                     // A1 ready; our GhB reads done
  if (tid == 0)
    __hip_atomic_store(flgW, (uint32_t)(T_+2), __ATOMIC_RELAXED, __HIP_MEMORY_SCOPE_AGENT);
  wait_for((uint32_t)(T_+2));                          // all WGs done reading GhB
  {
    f32x4 oacc = {0.f,0.f,0.f,0.f};
    #pragma unroll
    for (int ks = 0; ks < 8; ks++){
      const int kk = ks*32 + g*8;
      s16x8 a  = *(const s16x8*)&a1row[kk ^ sw];
      s16x8 bf = *(const s16x8*)&WFC[ul*256 + kk];
      oacc = mfma16(a, bf, oacc);
    }
    int n0 = Mt*16 + g*4;
    if (n0 < 24){
      #pragma unroll
      for (int r = 0; r < 4; r++)
        out[(size_t)b*6144 + (n0+r)*256 + ug] = ftanh_(oacc[r] + bfcl);
    }
  }
}

extern "C" void kernel_launch(void* const* d_in, const int* in_sizes, int n_in,
                              void* d_out, int out_size, void* d_ws, size_t ws_size,
                              hipStream_t stream)
{
  (void)in_sizes; (void)n_in; (void)out_size;
  if (ws_size < WS_NEED) return;   // loud failure via validation rather than OOB

  const float* x   = (const float*)d_in[0];
  const float* G   = (const float*)d_in[1];
  const float* Wih = (const float*)d_in[2];
  const float* bih = (const float*)d_in[3];
  const float* Whh = (const float*)d_in[4];
  const float* bhh = (const float*)d_in[5];
  const float* Wh1 = (const float*)d_in[6];
  const float* bh1 = (const float*)d_in[7];
  const float* Wh2 = (const float*)d_in[8];
  const float* bh2 = (const float*)d_in[9];
  const float* Wfc = (const float*)d_in[10];
  const float* bfc = (const float*)d_in[11];
  uint8_t* ws = (uint8_t*)d_ws;
  float* outp = (float*)d_out;

  hipLaunchKernelGGL(prep_kernel, dim3(256), dim3(256), 0, stream,
                     G, Wih, Whh, Wh1, Wh2, Wfc, ws);

  hipFuncSetAttribute((const void*)encoder_kernel,
                      hipFuncAttributeMaxDynamicSharedMemorySize, L_TOT);
  void* args[] = {(void*)&x, (void*)&ws, (void*)&outp,
                  (void*)&bih, (void*)&bhh, (void*)&bh1, (void*)&bh2, (void*)&bfc};
  hipLaunchCooperativeKernel((const void*)encoder_kernel, dim3(256), dim3(512),
                             args, L_TOT, stream);
}